// Round 7
// baseline (21.544 us; speedup 1.0000x reference)
//
#include <hip/hip_runtime.h>

// Aggregation: out[b,c,oh,ow] = sum_{i,j in 0..2} xpad[b,c,oh+i,ow+j] * w[b, c%16, i*3+j, oh*64+ow]
// B=8, C=256, H=W=OH=OW=64, WC=16, G=16, K=3, PAD=1, STRIDE=1, DIL=1.
//
// R7: R6 geometry (1024 blocks, 256 thr, LDS 40960 B = 4 blocks/CU, weight read once) plus:
//  - DPP halo shuffles: e0/e5 come from neighbor lanes' registers (row_shr:1 / row_shl:1,
//    bound_ctrl=1 zeroes row-boundary lanes = exactly the width-pad semantics). Removes all
//    48 bank-conflicted b32 LDS reads + cndmasks per thread.
//  - Channel-half pipeline (T14): stage h0 -> barrier -> {issue h1 loads, compute h0,
//    ds_write h1} -> barrier -> compute h1. Halves are disjoint LDS regions (race-free);
//    h1 global loads stay in flight across compute h0.
//  - XCD-chunked block swizzle (T1): logical-consecutive blocks (strips sharing x halo rows)
//    land on the same XCD. Bijective (1024 % 8 == 0).
// Thread map: tid = c4sel(1b) | row(3b) | l16(4b). Per phase: 4 channels x 1 row x 4 cols.

#define NB 8
#define NC 256
#define NH 64
#define NW 64
#define NWC 16
#define NG 16
#define STRIP 8
#define LCHR 10              // 8 rows + 2 halo
#define LROW 64
#define LCH (LCHR * LROW)    // 640 floats per channel
#define HCH 8                // channels per half

__device__ __forceinline__ float dpp_shr1(float v) {   // lane i <- lane i-1 (16-lane rows), boundary -> 0
    return __int_as_float(__builtin_amdgcn_update_dpp(
        0, __float_as_int(v), 0x111, 0xf, 0xf, true));
}
__device__ __forceinline__ float dpp_shl1(float v) {   // lane i <- lane i+1 (16-lane rows), boundary -> 0
    return __int_as_float(__builtin_amdgcn_update_dpp(
        0, __float_as_int(v), 0x101, 0xf, 0xf, true));
}

__global__ __launch_bounds__(256, 4) void agg_kernel(const float* __restrict__ x,
                                                     const float* __restrict__ wt,
                                                     float* __restrict__ out) {
    __shared__ float lds[NG * LCH];   // 10240 floats = 40960 B exactly

    const int tid   = threadIdx.x;
    const int l16   = tid & 15;
    const int row   = (tid >> 4) & 7;
    const int c4sel = tid >> 7;        // 0/1: which 4-channel quarter within each half

    // XCD-chunked swizzle: hw blocks {r, r+8, r+16, ...} -> XCD r get logical chunk r*128..
    const int hw    = blockIdx.x;
    const int bid   = (hw & 7) * 128 + (hw >> 3);
    const int strip = bid & 7;         // 8 strips of 8 rows
    const int wc    = (bid >> 3) & 15;
    const int b     = bid >> 7;

    const int oh  = strip * STRIP + row;
    const int ow0 = l16 * 4;
    const int r0  = strip * STRIP - 1;   // global row of LDS row 0

    // ---- staging helper: half h, item k (8ch x 10r x 16 f4 = 1280 f4 per half, 5/thread) ----
    auto stage_issue = [&](int k, int half, float4& v, int& addr) {
        const int f   = tid + k * 256;   // 0..1279
        const int ch  = f / 160;         // 0..7 within half
        const int rem = f - ch * 160;
        const int r   = rem >> 4;        // 0..9
        const int c4  = rem & 15;
        const int gr  = r0 + r;
        v = make_float4(0.f, 0.f, 0.f, 0.f);
        if ((unsigned)gr < (unsigned)NH) {
            const int c = (half * HCH + ch) * NWC + wc;
            v = *reinterpret_cast<const float4*>(
                x + (((b * NC + c) * NH + gr) * NW) + c4 * 4);
        }
        addr = (half * HCH + ch) * LCH + r * LROW + c4 * 4;
    };

    // ---- phase A: issue half0 stage loads, then weights ----
    float4 s0[5]; int a0[5];
#pragma unroll
    for (int k = 0; k < 5; ++k) stage_issue(k, 0, s0[k], a0[k]);

    float w[9][4];
    {
        const float* wp = wt + ((b * NWC + wc) * 9) * (NH * NW) + oh * NW + ow0;
#pragma unroll
        for (int idx = 0; idx < 9; ++idx) {
            float4 t = *reinterpret_cast<const float4*>(wp + idx * (NH * NW));
            w[idx][0] = t.x; w[idx][1] = t.y; w[idx][2] = t.z; w[idx][3] = t.w;
        }
    }

#pragma unroll
    for (int k = 0; k < 5; ++k) *reinterpret_cast<float4*>(&lds[a0[k]]) = s0[k];

    // ---- compute helper: 4 channels x 4 outputs for one half ----
    auto compute_half = [&](int half) {
#pragma unroll
        for (int cc = 0; cc < 4; ++cc) {
            const int g = half * HCH + c4sel * 4 + cc;
            const float* pch = &lds[g * LCH];
            float acc[4] = {0.f, 0.f, 0.f, 0.f};
#pragma unroll
            for (int i = 0; i < 3; ++i) {
                const float* p = pch + (row + i) * LROW + ow0;
                float4 m = *reinterpret_cast<const float4*>(p);
                const float e0 = dpp_shr1(m.w);   // x[ow0-1] from lane-1; 0 at l16==0
                const float e5 = dpp_shl1(m.x);   // x[ow0+4] from lane+1; 0 at l16==15
                const float e[6] = {e0, m.x, m.y, m.z, m.w, e5};
#pragma unroll
                for (int j = 0; j < 3; ++j) {
                    const float* wj = w[i * 3 + j];
                    acc[0] += e[0 + j] * wj[0];
                    acc[1] += e[1 + j] * wj[1];
                    acc[2] += e[2 + j] * wj[2];
                    acc[3] += e[3 + j] * wj[3];
                }
            }
            float* op = out + (((b * NC + g * NWC + wc) * NH + oh) * NW) + ow0;
            *reinterpret_cast<float4*>(op) = make_float4(acc[0], acc[1], acc[2], acc[3]);
        }
    };

    __syncthreads();

    // ---- phase B: issue half1 loads; compute half0 (overlaps load latency); write half1 ----
    float4 s1[5]; int a1[5];
#pragma unroll
    for (int k = 0; k < 5; ++k) stage_issue(k, 1, s1[k], a1[k]);

    compute_half(0);

#pragma unroll
    for (int k = 0; k < 5; ++k) *reinterpret_cast<float4*>(&lds[a1[k]]) = s1[k];

    __syncthreads();

    // ---- phase C: compute half1 ----
    compute_half(1);
}

extern "C" void kernel_launch(void* const* d_in, const int* in_sizes, int n_in,
                              void* d_out, int out_size, void* d_ws, size_t ws_size,
                              hipStream_t stream) {
    const float* x  = (const float*)d_in[0];
    const float* wt = (const float*)d_in[1];
    float* out      = (float*)d_out;

    // Grid: 1024 blocks of 256 threads = exactly 4 blocks/CU, one round.
    dim3 grid(NB * NWC * 8);
    dim3 block(256);
    agg_kernel<<<grid, block, 0, stream>>>(x, wt, out);
}

// Round 9
// 20.831 us; speedup vs baseline: 1.0342x; 1.0342x over previous
//
#include <hip/hip_runtime.h>

// Aggregation: out[b,c,oh,ow] = sum_{i,j in 0..2} xpad[b,c,oh+i,ow+j] * w[b, c%16, i*3+j, oh*64+ow]
// B=8, C=256, H=W=OH=OW=64, WC=16, G=16, K=3, PAD=1, STRIDE=1, DIL=1.
//
// R8b: byte-minimal geometry (R8 with the nontemporal-store type fixed).
// Block = (b, wc, 16-row quarter); each (row,l16) pixel owned by exactly ONE thread
// computing ALL 16 channels -> weight read EXACTLY once (R7 read it 2x), vertical halo
// halved (2/16 vs 2/8). App bytes 113 -> 88 MB.
// LDS = 16ch x 18rows x 64 floats = 73728 B -> exactly 2 blocks/CU; grid 512 = 2/CU, no tail.
// Halos via DPP lane shuffles (R7-proven, LDS-free, boundary lanes auto-zeroed).
// Output stores nontemporal (streamed, never re-read) to keep x/w L2-resident.

#define NB 8
#define NC 256
#define NH 64
#define NW 64
#define NWC 16
#define NG 16
#define STRIP 16
#define LCHR 18              // 16 rows + 2 halo
#define LROW 64
#define LCH (LCHR * LROW)    // 1152 floats per channel

typedef float f32x4 __attribute__((ext_vector_type(4)));

__device__ __forceinline__ float dpp_shr1(float v) {   // lane i <- lane i-1 (16-lane rows), boundary -> 0
    return __int_as_float(__builtin_amdgcn_update_dpp(
        0, __float_as_int(v), 0x111, 0xf, 0xf, true));
}
__device__ __forceinline__ float dpp_shl1(float v) {   // lane i <- lane i+1 (16-lane rows), boundary -> 0
    return __int_as_float(__builtin_amdgcn_update_dpp(
        0, __float_as_int(v), 0x101, 0xf, 0xf, true));
}

__global__ __launch_bounds__(256, 2) void agg_kernel(const float* __restrict__ x,
                                                     const float* __restrict__ wt,
                                                     float* __restrict__ out) {
    __shared__ float lds[NG * LCH];   // 18432 floats = 73728 B

    const int tid = threadIdx.x;
    const int l16 = tid & 15;
    const int row = tid >> 4;          // 0..15

    // XCD-chunked swizzle (bijective, 512 % 8 == 0): consecutive logical blocks
    // (quarters sharing x halo rows) land on the same XCD for L2 halo hits.
    const int hw   = blockIdx.x;
    const int bid  = (hw & 7) * 64 + (hw >> 3);
    const int q    = bid & 3;          // 4 quarters of 16 rows
    const int wc   = (bid >> 2) & 15;
    const int b    = bid >> 6;

    const int oh  = q * STRIP + row;
    const int ow0 = l16 * 4;
    const int r0  = q * STRIP - 1;     // global row of LDS row 0

    // ---- issue ALL stage loads (MLP): 16ch x 18r x 16 f4 = 4608 f4, 18/thread ----
    float4 sv[18];
    int    laddr[18];
#pragma unroll
    for (int k = 0; k < 18; ++k) {
        const int f   = tid + k * 256;   // 0..4607
        const int ch  = f / 288;         // 288 f4 per channel (18 rows x 16)
        const int rem = f - ch * 288;
        const int r   = rem >> 4;        // 0..17
        const int c4  = rem & 15;
        const int gr  = r0 + r;
        float4 v = make_float4(0.f, 0.f, 0.f, 0.f);
        if ((unsigned)gr < (unsigned)NH) {
            const int c = ch * NWC + wc;
            v = *reinterpret_cast<const float4*>(
                x + (((b * NC + c) * NH + gr) * NW) + c4 * 4);
        }
        sv[k]    = v;
        laddr[k] = ch * LCH + r * LROW + c4 * 4;
    }

    // ---- weights: 9 taps x 4 cols, read EXACTLY once per output pixel-quad ----
    float w[9][4];
    {
        const float* wp = wt + ((b * NWC + wc) * 9) * (NH * NW) + oh * NW + ow0;
#pragma unroll
        for (int idx = 0; idx < 9; ++idx) {
            float4 t = *reinterpret_cast<const float4*>(wp + idx * (NH * NW));
            w[idx][0] = t.x; w[idx][1] = t.y; w[idx][2] = t.z; w[idx][3] = t.w;
        }
    }

    // ---- LDS writes ----
#pragma unroll
    for (int k = 0; k < 18; ++k) {
        *reinterpret_cast<float4*>(&lds[laddr[k]]) = sv[k];
    }

    __syncthreads();

    // ---- compute: 16 channels x 4 outputs per thread ----
#pragma unroll
    for (int ch = 0; ch < NG; ++ch) {
        const float* pch = &lds[ch * LCH];
        float acc[4] = {0.f, 0.f, 0.f, 0.f};

#pragma unroll
        for (int i = 0; i < 3; ++i) {
            const float* p = pch + (row + i) * LROW + ow0;
            float4 m = *reinterpret_cast<const float4*>(p);
            const float e0 = dpp_shr1(m.w);   // x[ow0-1] from lane-1; 0 at l16==0
            const float e5 = dpp_shl1(m.x);   // x[ow0+4] from lane+1; 0 at l16==15
            const float e[6] = {e0, m.x, m.y, m.z, m.w, e5};
#pragma unroll
            for (int j = 0; j < 3; ++j) {
                const float* wj = w[i * 3 + j];
                acc[0] += e[0 + j] * wj[0];
                acc[1] += e[1 + j] * wj[1];
                acc[2] += e[2 + j] * wj[2];
                acc[3] += e[3 + j] * wj[3];
            }
        }

        float* op = out + (((b * NC + ch * NWC + wc) * NH + oh) * NW) + ow0;
        f32x4 o = {acc[0], acc[1], acc[2], acc[3]};
        __builtin_nontemporal_store(o, reinterpret_cast<f32x4*>(op));
    }
}

extern "C" void kernel_launch(void* const* d_in, const int* in_sizes, int n_in,
                              void* d_out, int out_size, void* d_ws, size_t ws_size,
                              hipStream_t stream) {
    const float* x  = (const float*)d_in[0];
    const float* wt = (const float*)d_in[1];
    float* out      = (float*)d_out;

    // Grid: 8 b * 16 wc * 4 quarters = 512 blocks of 256 threads = exactly 2 blocks/CU.
    dim3 grid(NB * NWC * 4);
    dim3 block(256);
    agg_kernel<<<grid, block, 0, stream>>>(x, wt, out);
}